// Round 6
// baseline (861.854 us; speedup 1.0000x reference)
//
#include <hip/hip_runtime.h>
#include <hip/hip_bf16.h>

#define VOCAB 32000
#define EMB   64
#define HID   64
#define NB    16
#define NS    256
#define G3    192   // 3*HID
#define MT    4     // mtiles per k_logits block (w_out reuse factor)

typedef __bf16 bf16x8  __attribute__((ext_vector_type(8)));
typedef short  short8  __attribute__((ext_vector_type(8)));
typedef short  short4v __attribute__((ext_vector_type(4)));
typedef float  floatx4 __attribute__((ext_vector_type(4)));
typedef float  floatx2 __attribute__((ext_vector_type(2)));

__device__ __forceinline__ float bf2f(__hip_bfloat16 v) { return __bfloat162float(v); }

// RNE fp32 -> bf16 bit pattern (no NaN inputs possible here)
__device__ __forceinline__ short f2bf_bits(float f) {
    unsigned int u = __float_as_uint(f);
    unsigned int r = (u + 0x7FFFu + ((u >> 16) & 1u)) >> 16;
    return (short)r;
}

// Runtime dtype detection: true if the array at p holds bf16 data, false if fp32.
__device__ __forceinline__ bool detect_bf16(const void* p) {
    const unsigned int* w = (const unsigned int*)p;
    unsigned int word = w[threadIdx.x & 63];
    unsigned int e = (word >> 7) & 0xFFu;
    int pred = (e >= 115u) && (e <= 130u);
    unsigned long long m = __ballot(pred);
    return __popcll(m) > 32;
}

// lane-broadcast of a float via v_readlane (result wave-uniform -> SGPR)
__device__ __forceinline__ float bcastf(float v, int l) {
    return __uint_as_float(__builtin_amdgcn_readlane(__float_as_uint(v), l));
}

// ---------------------------------------------------------------------------
// K1: xpt[s][gate][b][u] = sum_e emb[tok[b][s]][e] * w_ih[gate*64+u][e] + b_ih
// Transposed layout: K2's lanes (u contiguous) read 256B-coalesced rows.
// ---------------------------------------------------------------------------
__global__ __launch_bounds__(G3) void k_embed_proj_t(
    const int* __restrict__ tokens,
    const void* __restrict__ emb_raw,
    const void* __restrict__ w_ih_raw,
    const void* __restrict__ b_ih_raw,
    float* __restrict__ xpt)
{
    const bool isbf = detect_bf16(w_ih_raw);
    const int s   = blockIdx.x;
    const int tid = threadIdx.x;

    __shared__ int   tok_s[NB];
    __shared__ float e_s[NB][EMB];

    if (tid < NB) tok_s[tid] = tokens[tid * NS + s];
    __syncthreads();
    for (int idx = tid; idx < NB * EMB; idx += G3) {
        const int b = idx >> 6, e = idx & 63;
        const int t = tok_s[b];
        e_s[b][e] = isbf ? bf2f(((const __hip_bfloat16*)emb_raw)[t * EMB + e])
                         : ((const float*)emb_raw)[t * EMB + e];
    }
    __syncthreads();

    float wf[EMB];
    if (isbf) {
        const __hip_bfloat16* wrow = (const __hip_bfloat16*)w_ih_raw + tid * EMB;
#pragma unroll
        for (int k0 = 0; k0 < EMB; k0 += 8) {
            bf16x8 wv = *reinterpret_cast<const bf16x8*>(wrow + k0);
#pragma unroll
            for (int j = 0; j < 8; ++j) wf[k0 + j] = (float)wv[j];
        }
    } else {
        const float* wrow = (const float*)w_ih_raw + tid * EMB;
#pragma unroll
        for (int k0 = 0; k0 < EMB; k0 += 4) {
            floatx4 wv = *reinterpret_cast<const floatx4*>(wrow + k0);
#pragma unroll
            for (int j = 0; j < 4; ++j) wf[k0 + j] = wv[j];
        }
    }
    const float bias = isbf ? bf2f(((const __hip_bfloat16*)b_ih_raw)[tid])
                            : ((const float*)b_ih_raw)[tid];

    const int gam = tid >> 6;       // gate 0..2 (r,z,n)
    const int u   = tid & 63;       // unit
    float* orow = xpt + ((size_t)(s * 3 + gam) * NB) * HID + u;
    for (int b = 0; b < NB; ++b) {
        float acc = bias;
#pragma unroll
        for (int k0 = 0; k0 < EMB; k0 += 4) {
            floatx4 e4 = *reinterpret_cast<const floatx4*>(&e_s[b][k0]);
            acc += e4[0] * wf[k0] + e4[1] * wf[k0 + 1]
                 + e4[2] * wf[k0 + 2] + e4[3] * wf[k0 + 3];
        }
        orow[b * HID] = acc;   // lanes u=0..63 contiguous -> 256B coalesced
    }
}

// ---------------------------------------------------------------------------
// K2: sequential GRU scan. Loop body IDENTICAL to the measured R5 version;
// ONLY the launch config changes: 512-thread blocks (8 waves = 2 waves/SIMD),
// grid = 2, each wave owns one batch, zero barriers/LDS. Two independent
// scans per SIMD interleave so dependent-chain latency (readlane->FMA,
// exp->div->h) of one wave hides under the other's issue.
// __launch_bounds__(512,2) caps VGPR at 256 (usage ~250, no spill).
// ---------------------------------------------------------------------------
__global__ __launch_bounds__(512, 2) void k_gru_scan(
    const float* __restrict__ xpt,
    const void* __restrict__ w_hh_raw,
    const void* __restrict__ b_hh_raw,
    __hip_bfloat16* __restrict__ hs)
{
    const bool isbf = detect_bf16(w_hh_raw);
    const int b = blockIdx.x * 8 + (threadIdx.x >> 6);   // wave -> batch
    const int j = threadIdx.x & 63;                      // owns hidden unit j

    floatx2 wr2[HID / 2], wz2[HID / 2], wn2[HID / 2];
    if (isbf) {
        const __hip_bfloat16* w = (const __hip_bfloat16*)w_hh_raw;
#pragma unroll
        for (int k0 = 0; k0 < HID; k0 += 8) {
            bf16x8 v0 = *reinterpret_cast<const bf16x8*>(w + (          j) * HID + k0);
            bf16x8 v1 = *reinterpret_cast<const bf16x8*>(w + (HID     + j) * HID + k0);
            bf16x8 v2 = *reinterpret_cast<const bf16x8*>(w + (2 * HID + j) * HID + k0);
#pragma unroll
            for (int t = 0; t < 4; ++t) {
                wr2[(k0 >> 1) + t] = (floatx2){(float)v0[2 * t], (float)v0[2 * t + 1]};
                wz2[(k0 >> 1) + t] = (floatx2){(float)v1[2 * t], (float)v1[2 * t + 1]};
                wn2[(k0 >> 1) + t] = (floatx2){(float)v2[2 * t], (float)v2[2 * t + 1]};
            }
        }
    } else {
        const float* w = (const float*)w_hh_raw;
#pragma unroll
        for (int k0 = 0; k0 < HID; k0 += 4) {
            floatx4 v0 = *reinterpret_cast<const floatx4*>(w + (          j) * HID + k0);
            floatx4 v1 = *reinterpret_cast<const floatx4*>(w + (HID     + j) * HID + k0);
            floatx4 v2 = *reinterpret_cast<const floatx4*>(w + (2 * HID + j) * HID + k0);
#pragma unroll
            for (int t = 0; t < 2; ++t) {
                wr2[(k0 >> 1) + t] = (floatx2){v0[2 * t], v0[2 * t + 1]};
                wz2[(k0 >> 1) + t] = (floatx2){v1[2 * t], v1[2 * t + 1]};
                wn2[(k0 >> 1) + t] = (floatx2){v2[2 * t], v2[2 * t + 1]};
            }
        }
    }

    float bhr, bhz, bhn;
    if (isbf) {
        const __hip_bfloat16* bb = (const __hip_bfloat16*)b_hh_raw;
        bhr = bf2f(bb[j]); bhz = bf2f(bb[HID + j]); bhn = bf2f(bb[2 * HID + j]);
    } else {
        const float* bb = (const float*)b_hh_raw;
        bhr = bb[j]; bhz = bb[HID + j]; bhn = bb[2 * HID + j];
    }

    // xpt layout: [s][gate][b][u] -> lanes u contiguous (256B coalesced)
    const float* xbase = xpt + (size_t)b * HID + j;
#define XLD(s, g) xbase[((size_t)((s) * 3 + (g)) * NB) * HID]

    float xc0 = XLD(0, 0), xc1 = XLD(0, 1), xc2 = XLD(0, 2);
    float xn0 = XLD(1, 0), xn1 = XLD(1, 1), xn2 = XLD(1, 2);
    float h = 0.f;

    for (int s = 0; s < NS; ++s) {
        // depth-2 prefetch: loads for step s+2 fly across ~2 iterations
        float pf0 = 0.f, pf1 = 0.f, pf2 = 0.f;
        if (s + 2 < NS) {
            pf0 = XLD(s + 2, 0); pf1 = XLD(s + 2, 1); pf2 = XLD(s + 2, 2);
        }

        floatx2 ar0 = {0.f, 0.f}, ar1 = {0.f, 0.f};
        floatx2 az0 = {0.f, 0.f}, az1 = {0.f, 0.f};
        floatx2 an0 = {0.f, 0.f}, an1 = {0.f, 0.f};
#pragma unroll
        for (int kk = 0; kk < HID; kk += 16) {
            // batch 16 independent broadcasts -> SGPRs (pipelined)
            float hb[16];
#pragma unroll
            for (int t = 0; t < 16; ++t) hb[t] = bcastf(h, kk + t);
#pragma unroll
            for (int p = 0; p < 8; ++p) {
                const int w = (kk >> 1) + p;
                floatx2 hv;
                hv[0] = hb[2 * p];
                hv[1] = hb[2 * p + 1];
                if (p & 1) { ar1 += hv * wr2[w]; az1 += hv * wz2[w]; an1 += hv * wn2[w]; }
                else       { ar0 += hv * wr2[w]; az0 += hv * wz2[w]; an0 += hv * wn2[w]; }
            }
        }
        const float arf = (ar0[0] + ar0[1]) + (ar1[0] + ar1[1]);
        const float azf = (az0[0] + az0[1]) + (az1[0] + az1[1]);
        const float anf = (an0[0] + an0[1]) + (an1[0] + an1[1]);

        const float r = __fdividef(1.f, 1.f + __expf(-(xc0 + arf + bhr)));
        const float z = __fdividef(1.f, 1.f + __expf(-(xc1 + azf + bhz)));
        const float n = __fdividef(2.f, 1.f + __expf(-2.f * (xc2 + r * (anf + bhn)))) - 1.f;
        h = (1.f - z) * n + z * h;

        hs[((size_t)b * NS + s) * HID + j] = __float2bfloat16(h);

        // rotate the register pipeline (all static)
        xc0 = xn0; xc1 = xn1; xc2 = xn2;
        xn0 = pf0; xn1 = pf1; xn2 = pf2;
    }
#undef XLD
}

// ---------------------------------------------------------------------------
// K3: out[m][v] = sum_k hs[m][k] * w_out[v][k] + b_out[v].
// Each block processes MT=4 mtiles (64 rows) x 256 cols with the SAME
// in-register w_out B-fragments. Grid: x = mtile-group (fast), y = ncb ->
// consecutive blocks share a w_out slice per XCD L2.
// Stores staged through LDS -> 256B-contiguous nontemporal row writes.
// ---------------------------------------------------------------------------
__global__ __launch_bounds__(256) void k_logits(
    const __hip_bfloat16* __restrict__ hs,
    const void* __restrict__ w_out_raw,
    const void* __restrict__ b_out_raw,
    void* __restrict__ out_raw)
{
    const bool isbf = detect_bf16(w_out_raw);
    const int mg    = blockIdx.x;            // 0..63  (4 mtiles = 64 rows each)
    const int ncb   = blockIdx.y;            // 0..124 (256 cols each)
    const int wave  = threadIdx.x >> 6;      // 0..3
    const int lane  = threadIdx.x & 63;
    const int quad  = lane >> 4;
    const int l15   = lane & 15;

    __shared__ float tile[4][16][68];

    const int ncol_wave = ncb * 256 + wave * 64;

    // --- load B-fragments + bias ONCE, reuse across MT mtiles ---
    bf16x8 B0[4], B1[4];
    float biasv[4];
#pragma unroll
    for (int t = 0; t < 4; ++t) {
        const int ncol = ncol_wave + t * 16;
        if (isbf) {
            const __hip_bfloat16* brow = (const __hip_bfloat16*)w_out_raw + (ncol + l15) * HID;
            B0[t] = *reinterpret_cast<const bf16x8*>(brow + quad * 8);
            B1[t] = *reinterpret_cast<const bf16x8*>(brow + 32 + quad * 8);
            biasv[t] = bf2f(((const __hip_bfloat16*)b_out_raw)[ncol + l15]);
        } else {
            const float* browf = (const float*)w_out_raw + (ncol + l15) * HID;
            floatx4 f0 = *reinterpret_cast<const floatx4*>(browf + quad * 8);
            floatx4 f1 = *reinterpret_cast<const floatx4*>(browf + quad * 8 + 4);
            floatx4 f2 = *reinterpret_cast<const floatx4*>(browf + 32 + quad * 8);
            floatx4 f3 = *reinterpret_cast<const floatx4*>(browf + 32 + quad * 8 + 4);
            short8 s0, s1;
#pragma unroll
            for (int jj = 0; jj < 4; ++jj) {
                s0[jj] = f2bf_bits(f0[jj]); s0[4 + jj] = f2bf_bits(f1[jj]);
                s1[jj] = f2bf_bits(f2[jj]); s1[4 + jj] = f2bf_bits(f3[jj]);
            }
            B0[t] = __builtin_bit_cast(bf16x8, s0);
            B1[t] = __builtin_bit_cast(bf16x8, s1);
            biasv[t] = ((const float*)b_out_raw)[ncol + l15];
        }
    }

#pragma unroll
    for (int mt = 0; mt < MT; ++mt) {
        const int mtile = mg * MT + mt;
        const __hip_bfloat16* arow = hs + (mtile * 16 + l15) * HID;
        const bf16x8 a0 = *reinterpret_cast<const bf16x8*>(arow + quad * 8);
        const bf16x8 a1 = *reinterpret_cast<const bf16x8*>(arow + 32 + quad * 8);

#pragma unroll
        for (int t = 0; t < 4; ++t) {
            floatx4 acc = {0.f, 0.f, 0.f, 0.f};
            acc = __builtin_amdgcn_mfma_f32_16x16x32_bf16(a0, B0[t], acc, 0, 0, 0);
            acc = __builtin_amdgcn_mfma_f32_16x16x32_bf16(a1, B1[t], acc, 0, 0, 0);
            // C layout: col = lane&15, row = quad*4 + i  ->  stage into LDS
#pragma unroll
            for (int i = 0; i < 4; ++i)
                tile[wave][quad * 4 + i][t * 16 + l15] = acc[i] + biasv[t];
        }
        __syncthreads();

        // Coalesced nontemporal writeback: quad q writes row p*4+q, 64 lanes
        // cover 256 B contiguous per row -> full cache lines past L2.
        if (isbf) {
            short* outb = (short*)out_raw;
#pragma unroll
            for (int p = 0; p < 4; ++p) {
                const int row = p * 4 + quad;
                const float* src = &tile[wave][row][l15 * 4];
                short4v u;
#pragma unroll
                for (int jj = 0; jj < 4; ++jj) u[jj] = f2bf_bits(src[jj]);
                __builtin_nontemporal_store(u, reinterpret_cast<short4v*>(
                    outb + (size_t)(mtile * 16 + row) * VOCAB + ncol_wave + l15 * 4));
            }
        } else {
            float* outf = (float*)out_raw;
#pragma unroll
            for (int p = 0; p < 4; ++p) {
                const int row = p * 4 + quad;
                floatx4 v = *reinterpret_cast<const floatx4*>(&tile[wave][row][l15 * 4]);
                __builtin_nontemporal_store(v, reinterpret_cast<floatx4*>(
                    outf + (size_t)(mtile * 16 + row) * VOCAB + ncol_wave + l15 * 4));
            }
        }
        __syncthreads();   // protect tile[] before next mt overwrites it
    }
}

// ---------------------------------------------------------------------------
extern "C" void kernel_launch(void* const* d_in, const int* in_sizes, int n_in,
                              void* d_out, int out_size, void* d_ws, size_t ws_size,
                              hipStream_t stream)
{
    const int*  tokens = (const int*)d_in[0];
    const void* emb    = d_in[1];
    const void* w_ih   = d_in[2];
    const void* w_hh   = d_in[3];
    const void* b_ih   = d_in[4];
    const void* b_hh   = d_in[5];
    const void* w_out  = d_in[6];
    const void* b_out  = d_in[7];

    // xpt scratch (3 MiB, layout [s][gate][b][u]) lives in d_out's head; it is
    // consumed by k_gru_scan before k_logits overwrites all of d_out.
    float* xpt = (float*)d_out;
    __hip_bfloat16* hs = (__hip_bfloat16*)d_ws;

    k_embed_proj_t<<<NS, G3, 0, stream>>>(tokens, emb, w_ih, b_ih, xpt);
    k_gru_scan<<<NB / 8, 512, 0, stream>>>(xpt, w_hh, b_hh, hs);
    dim3 grid3((NB * NS) / (16 * MT), VOCAB / 256);   // x = mtile-group (fast), y = ncb
    k_logits<<<grid3, 256, 0, stream>>>(hs, w_out, b_out, d_out);
}

// Round 7
// 799.176 us; speedup vs baseline: 1.0784x; 1.0784x over previous
//
#include <hip/hip_runtime.h>
#include <hip/hip_bf16.h>

#define VOCAB 32000
#define EMB   64
#define HID   64
#define NB    16
#define NS    256
#define G3    192   // 3*HID
#define MT    8     // mtiles per k_logits block (w_out reuse factor)

typedef __bf16 bf16x8  __attribute__((ext_vector_type(8)));
typedef short  short8  __attribute__((ext_vector_type(8)));
typedef short  short4v __attribute__((ext_vector_type(4)));
typedef float  floatx4 __attribute__((ext_vector_type(4)));
typedef float  floatx2 __attribute__((ext_vector_type(2)));

__device__ __forceinline__ float bf2f(__hip_bfloat16 v) { return __bfloat162float(v); }

// RNE fp32 -> bf16 bit pattern (no NaN inputs possible here)
__device__ __forceinline__ short f2bf_bits(float f) {
    unsigned int u = __float_as_uint(f);
    unsigned int r = (u + 0x7FFFu + ((u >> 16) & 1u)) >> 16;
    return (short)r;
}

// Runtime dtype detection: true if the array at p holds bf16 data, false if fp32.
__device__ __forceinline__ bool detect_bf16(const void* p) {
    const unsigned int* w = (const unsigned int*)p;
    unsigned int word = w[threadIdx.x & 63];
    unsigned int e = (word >> 7) & 0xFFu;
    int pred = (e >= 115u) && (e <= 130u);
    unsigned long long m = __ballot(pred);
    return __popcll(m) > 32;
}

// lane-broadcast of a float via v_readlane (result wave-uniform -> SGPR)
__device__ __forceinline__ float bcastf(float v, int l) {
    return __uint_as_float(__builtin_amdgcn_readlane(__float_as_uint(v), l));
}

// ---------------------------------------------------------------------------
// K1: xpt[s][gate][b][u] = sum_e emb[tok[b][s]][e] * w_ih[gate*64+u][e] + b_ih
// Transposed layout: K2's lanes (u contiguous) read 256B-coalesced rows.
// ---------------------------------------------------------------------------
__global__ __launch_bounds__(G3) void k_embed_proj_t(
    const int* __restrict__ tokens,
    const void* __restrict__ emb_raw,
    const void* __restrict__ w_ih_raw,
    const void* __restrict__ b_ih_raw,
    float* __restrict__ xpt)
{
    const bool isbf = detect_bf16(w_ih_raw);
    const int s   = blockIdx.x;
    const int tid = threadIdx.x;

    __shared__ int   tok_s[NB];
    __shared__ float e_s[NB][EMB];

    if (tid < NB) tok_s[tid] = tokens[tid * NS + s];
    __syncthreads();
    for (int idx = tid; idx < NB * EMB; idx += G3) {
        const int b = idx >> 6, e = idx & 63;
        const int t = tok_s[b];
        e_s[b][e] = isbf ? bf2f(((const __hip_bfloat16*)emb_raw)[t * EMB + e])
                         : ((const float*)emb_raw)[t * EMB + e];
    }
    __syncthreads();

    float wf[EMB];
    if (isbf) {
        const __hip_bfloat16* wrow = (const __hip_bfloat16*)w_ih_raw + tid * EMB;
#pragma unroll
        for (int k0 = 0; k0 < EMB; k0 += 8) {
            bf16x8 wv = *reinterpret_cast<const bf16x8*>(wrow + k0);
#pragma unroll
            for (int j = 0; j < 8; ++j) wf[k0 + j] = (float)wv[j];
        }
    } else {
        const float* wrow = (const float*)w_ih_raw + tid * EMB;
#pragma unroll
        for (int k0 = 0; k0 < EMB; k0 += 4) {
            floatx4 wv = *reinterpret_cast<const floatx4*>(wrow + k0);
#pragma unroll
            for (int j = 0; j < 4; ++j) wf[k0 + j] = wv[j];
        }
    }
    const float bias = isbf ? bf2f(((const __hip_bfloat16*)b_ih_raw)[tid])
                            : ((const float*)b_ih_raw)[tid];

    const int gam = tid >> 6;       // gate 0..2 (r,z,n)
    const int u   = tid & 63;       // unit
    float* orow = xpt + ((size_t)(s * 3 + gam) * NB) * HID + u;
    for (int b = 0; b < NB; ++b) {
        float acc = bias;
#pragma unroll
        for (int k0 = 0; k0 < EMB; k0 += 4) {
            floatx4 e4 = *reinterpret_cast<const floatx4*>(&e_s[b][k0]);
            acc += e4[0] * wf[k0] + e4[1] * wf[k0 + 1]
                 + e4[2] * wf[k0 + 2] + e4[3] * wf[k0 + 3];
        }
        orow[b * HID] = acc;   // lanes u=0..63 contiguous -> 256B coalesced
    }
}

// ---------------------------------------------------------------------------
// K2: sequential GRU scan. Back to 64-thread blocks (1 wave, VGPR cap 512 ->
// no spills; R6's 2-waves/SIMD at cap 256 spilled and regressed). NEW: each
// wave processes TWO batches interleaved. The 192-VGPR weight set is SHARED;
// only per-batch state duplicates (~60 VGPRs -> ~255 total). Two independent
// dependency chains per step (readlane->FMA-chain->exp->h) interleave, so
// one batch's latency hides under the other's issue.
// ---------------------------------------------------------------------------
__global__ __launch_bounds__(64, 1) void k_gru_scan(
    const float* __restrict__ xpt,
    const void* __restrict__ w_hh_raw,
    const void* __restrict__ b_hh_raw,
    __hip_bfloat16* __restrict__ hs)
{
    const bool isbf = detect_bf16(w_hh_raw);
    const int b0 = blockIdx.x * 2;       // this wave's two batches
    const int j  = threadIdx.x;          // 0..63, owns hidden unit j

    floatx2 wr2[HID / 2], wz2[HID / 2], wn2[HID / 2];
    if (isbf) {
        const __hip_bfloat16* w = (const __hip_bfloat16*)w_hh_raw;
#pragma unroll
        for (int k0 = 0; k0 < HID; k0 += 8) {
            bf16x8 v0 = *reinterpret_cast<const bf16x8*>(w + (          j) * HID + k0);
            bf16x8 v1 = *reinterpret_cast<const bf16x8*>(w + (HID     + j) * HID + k0);
            bf16x8 v2 = *reinterpret_cast<const bf16x8*>(w + (2 * HID + j) * HID + k0);
#pragma unroll
            for (int t = 0; t < 4; ++t) {
                wr2[(k0 >> 1) + t] = (floatx2){(float)v0[2 * t], (float)v0[2 * t + 1]};
                wz2[(k0 >> 1) + t] = (floatx2){(float)v1[2 * t], (float)v1[2 * t + 1]};
                wn2[(k0 >> 1) + t] = (floatx2){(float)v2[2 * t], (float)v2[2 * t + 1]};
            }
        }
    } else {
        const float* w = (const float*)w_hh_raw;
#pragma unroll
        for (int k0 = 0; k0 < HID; k0 += 4) {
            floatx4 v0 = *reinterpret_cast<const floatx4*>(w + (          j) * HID + k0);
            floatx4 v1 = *reinterpret_cast<const floatx4*>(w + (HID     + j) * HID + k0);
            floatx4 v2 = *reinterpret_cast<const floatx4*>(w + (2 * HID + j) * HID + k0);
#pragma unroll
            for (int t = 0; t < 2; ++t) {
                wr2[(k0 >> 1) + t] = (floatx2){v0[2 * t], v0[2 * t + 1]};
                wz2[(k0 >> 1) + t] = (floatx2){v1[2 * t], v1[2 * t + 1]};
                wn2[(k0 >> 1) + t] = (floatx2){v2[2 * t], v2[2 * t + 1]};
            }
        }
    }

    float bhr, bhz, bhn;
    if (isbf) {
        const __hip_bfloat16* bb = (const __hip_bfloat16*)b_hh_raw;
        bhr = bf2f(bb[j]); bhz = bf2f(bb[HID + j]); bhn = bf2f(bb[2 * HID + j]);
    } else {
        const float* bb = (const float*)b_hh_raw;
        bhr = bb[j]; bhz = bb[HID + j]; bhn = bb[2 * HID + j];
    }

    // xpt layout: [s][gate][b][u] -> lanes u contiguous (256B coalesced)
    const float* xbA = xpt + (size_t)b0 * HID + j;
    const float* xbB = xpt + (size_t)(b0 + 1) * HID + j;
#define XLDA(s, g) xbA[((size_t)((s) * 3 + (g)) * NB) * HID]
#define XLDB(s, g) xbB[((size_t)((s) * 3 + (g)) * NB) * HID]

    float xcA0 = XLDA(0, 0), xcA1 = XLDA(0, 1), xcA2 = XLDA(0, 2);
    float xcB0 = XLDB(0, 0), xcB1 = XLDB(0, 1), xcB2 = XLDB(0, 2);
    float xnA0 = XLDA(1, 0), xnA1 = XLDA(1, 1), xnA2 = XLDA(1, 2);
    float xnB0 = XLDB(1, 0), xnB1 = XLDB(1, 1), xnB2 = XLDB(1, 2);
    float hA = 0.f, hB = 0.f;

    for (int s = 0; s < NS; ++s) {
        // depth-2 prefetch for both batches (6 independent loads in flight)
        float pfA0 = 0.f, pfA1 = 0.f, pfA2 = 0.f;
        float pfB0 = 0.f, pfB1 = 0.f, pfB2 = 0.f;
        if (s + 2 < NS) {
            pfA0 = XLDA(s + 2, 0); pfA1 = XLDA(s + 2, 1); pfA2 = XLDA(s + 2, 2);
            pfB0 = XLDB(s + 2, 0); pfB1 = XLDB(s + 2, 1); pfB2 = XLDB(s + 2, 2);
        }

        floatx2 arA = {0.f, 0.f}, azA = {0.f, 0.f}, anA = {0.f, 0.f};
        floatx2 arB = {0.f, 0.f}, azB = {0.f, 0.f}, anB = {0.f, 0.f};
#pragma unroll
        for (int kk = 0; kk < HID; kk += 8) {
            // batch 8 broadcasts per scan (x2 scans) -> SGPRs, pipelined
            float ha[8], hbv[8];
#pragma unroll
            for (int t = 0; t < 8; ++t) ha[t]  = bcastf(hA, kk + t);
#pragma unroll
            for (int t = 0; t < 8; ++t) hbv[t] = bcastf(hB, kk + t);
#pragma unroll
            for (int p = 0; p < 4; ++p) {
                const int w = (kk >> 1) + p;
                floatx2 hvA, hvB;
                hvA[0] = ha[2 * p];  hvA[1] = ha[2 * p + 1];
                hvB[0] = hbv[2 * p]; hvB[1] = hbv[2 * p + 1];
                arA += hvA * wr2[w]; arB += hvB * wr2[w];
                azA += hvA * wz2[w]; azB += hvB * wz2[w];
                anA += hvA * wn2[w]; anB += hvB * wn2[w];
            }
        }
        const float arfA = arA[0] + arA[1], azfA = azA[0] + azA[1], anfA = anA[0] + anA[1];
        const float arfB = arB[0] + arB[1], azfB = azB[0] + azB[1], anfB = anB[0] + anB[1];

        const float rA = __fdividef(1.f, 1.f + __expf(-(xcA0 + arfA + bhr)));
        const float rB = __fdividef(1.f, 1.f + __expf(-(xcB0 + arfB + bhr)));
        const float zA = __fdividef(1.f, 1.f + __expf(-(xcA1 + azfA + bhz)));
        const float zB = __fdividef(1.f, 1.f + __expf(-(xcB1 + azfB + bhz)));
        const float nA = __fdividef(2.f, 1.f + __expf(-2.f * (xcA2 + rA * (anfA + bhn)))) - 1.f;
        const float nB = __fdividef(2.f, 1.f + __expf(-2.f * (xcB2 + rB * (anfB + bhn)))) - 1.f;
        hA = (1.f - zA) * nA + zA * hA;
        hB = (1.f - zB) * nB + zB * hB;

        hs[((size_t)b0 * NS + s) * HID + j]       = __float2bfloat16(hA);
        hs[((size_t)(b0 + 1) * NS + s) * HID + j] = __float2bfloat16(hB);

        // rotate both register pipelines (all static)
        xcA0 = xnA0; xcA1 = xnA1; xcA2 = xnA2;
        xcB0 = xnB0; xcB1 = xnB1; xcB2 = xnB2;
        xnA0 = pfA0; xnA1 = pfA1; xnA2 = pfA2;
        xnB0 = pfB0; xnB1 = pfB1; xnB2 = pfB2;
    }
#undef XLDA
#undef XLDB
}

// ---------------------------------------------------------------------------
// K3: out[m][v] = sum_k hs[m][k] * w_out[v][k] + b_out[v].
// Each block processes MT=8 mtiles (128 rows) x 256 cols with the SAME
// in-register w_out B-fragments -> logical w_out traffic 2.1GB/8 = 262 MB.
// Grid: x = mtile-group (fast), y = ncb -> consecutive blocks share a slice.
// Stores staged through LDS -> 256B-contiguous nontemporal row writes.
// ---------------------------------------------------------------------------
__global__ __launch_bounds__(256) void k_logits(
    const __hip_bfloat16* __restrict__ hs,
    const void* __restrict__ w_out_raw,
    const void* __restrict__ b_out_raw,
    void* __restrict__ out_raw)
{
    const bool isbf = detect_bf16(w_out_raw);
    const int mg    = blockIdx.x;            // 0..31  (8 mtiles = 128 rows each)
    const int ncb   = blockIdx.y;            // 0..124 (256 cols each)
    const int wave  = threadIdx.x >> 6;      // 0..3
    const int lane  = threadIdx.x & 63;
    const int quad  = lane >> 4;
    const int l15   = lane & 15;

    __shared__ float tile[4][16][68];

    const int ncol_wave = ncb * 256 + wave * 64;

    // --- load B-fragments + bias ONCE, reuse across MT mtiles ---
    bf16x8 B0[4], B1[4];
    float biasv[4];
#pragma unroll
    for (int t = 0; t < 4; ++t) {
        const int ncol = ncol_wave + t * 16;
        if (isbf) {
            const __hip_bfloat16* brow = (const __hip_bfloat16*)w_out_raw + (ncol + l15) * HID;
            B0[t] = *reinterpret_cast<const bf16x8*>(brow + quad * 8);
            B1[t] = *reinterpret_cast<const bf16x8*>(brow + 32 + quad * 8);
            biasv[t] = bf2f(((const __hip_bfloat16*)b_out_raw)[ncol + l15]);
        } else {
            const float* browf = (const float*)w_out_raw + (ncol + l15) * HID;
            floatx4 f0 = *reinterpret_cast<const floatx4*>(browf + quad * 8);
            floatx4 f1 = *reinterpret_cast<const floatx4*>(browf + quad * 8 + 4);
            floatx4 f2 = *reinterpret_cast<const floatx4*>(browf + 32 + quad * 8);
            floatx4 f3 = *reinterpret_cast<const floatx4*>(browf + 32 + quad * 8 + 4);
            short8 s0, s1;
#pragma unroll
            for (int jj = 0; jj < 4; ++jj) {
                s0[jj] = f2bf_bits(f0[jj]); s0[4 + jj] = f2bf_bits(f1[jj]);
                s1[jj] = f2bf_bits(f2[jj]); s1[4 + jj] = f2bf_bits(f3[jj]);
            }
            B0[t] = __builtin_bit_cast(bf16x8, s0);
            B1[t] = __builtin_bit_cast(bf16x8, s1);
            biasv[t] = ((const float*)b_out_raw)[ncol + l15];
        }
    }

#pragma unroll
    for (int mt = 0; mt < MT; ++mt) {
        const int mtile = mg * MT + mt;
        const __hip_bfloat16* arow = hs + (mtile * 16 + l15) * HID;
        const bf16x8 a0 = *reinterpret_cast<const bf16x8*>(arow + quad * 8);
        const bf16x8 a1 = *reinterpret_cast<const bf16x8*>(arow + 32 + quad * 8);

#pragma unroll
        for (int t = 0; t < 4; ++t) {
            floatx4 acc = {0.f, 0.f, 0.f, 0.f};
            acc = __builtin_amdgcn_mfma_f32_16x16x32_bf16(a0, B0[t], acc, 0, 0, 0);
            acc = __builtin_amdgcn_mfma_f32_16x16x32_bf16(a1, B1[t], acc, 0, 0, 0);
            // C layout: col = lane&15, row = quad*4 + i  ->  stage into LDS
#pragma unroll
            for (int i = 0; i < 4; ++i)
                tile[wave][quad * 4 + i][t * 16 + l15] = acc[i] + biasv[t];
        }
        __syncthreads();

        // Coalesced nontemporal writeback: quad q writes row p*4+q, 64 lanes
        // cover 256 B contiguous per row -> full cache lines past L2.
        if (isbf) {
            short* outb = (short*)out_raw;
#pragma unroll
            for (int p = 0; p < 4; ++p) {
                const int row = p * 4 + quad;
                const float* src = &tile[wave][row][l15 * 4];
                short4v u;
#pragma unroll
                for (int jj = 0; jj < 4; ++jj) u[jj] = f2bf_bits(src[jj]);
                __builtin_nontemporal_store(u, reinterpret_cast<short4v*>(
                    outb + (size_t)(mtile * 16 + row) * VOCAB + ncol_wave + l15 * 4));
            }
        } else {
            float* outf = (float*)out_raw;
#pragma unroll
            for (int p = 0; p < 4; ++p) {
                const int row = p * 4 + quad;
                floatx4 v = *reinterpret_cast<const floatx4*>(&tile[wave][row][l15 * 4]);
                __builtin_nontemporal_store(v, reinterpret_cast<floatx4*>(
                    outf + (size_t)(mtile * 16 + row) * VOCAB + ncol_wave + l15 * 4));
            }
        }
        __syncthreads();   // protect tile[] before next mt overwrites it
    }
}

// ---------------------------------------------------------------------------
extern "C" void kernel_launch(void* const* d_in, const int* in_sizes, int n_in,
                              void* d_out, int out_size, void* d_ws, size_t ws_size,
                              hipStream_t stream)
{
    const int*  tokens = (const int*)d_in[0];
    const void* emb    = d_in[1];
    const void* w_ih   = d_in[2];
    const void* w_hh   = d_in[3];
    const void* b_ih   = d_in[4];
    const void* b_hh   = d_in[5];
    const void* w_out  = d_in[6];
    const void* b_out  = d_in[7];

    // xpt scratch (3 MiB, layout [s][gate][b][u]) lives in d_out's head; it is
    // consumed by k_gru_scan before k_logits overwrites all of d_out.
    float* xpt = (float*)d_out;
    __hip_bfloat16* hs = (__hip_bfloat16*)d_ws;

    k_embed_proj_t<<<NS, G3, 0, stream>>>(tokens, emb, w_ih, b_ih, xpt);
    k_gru_scan<<<NB / 2, 64, 0, stream>>>(xpt, w_hh, b_hh, hs);
    dim3 grid3((NB * NS) / (16 * MT), VOCAB / 256);   // x = mtile-group (fast), y = ncb
    k_logits<<<grid3, 256, 0, stream>>>(hs, w_out, b_out, d_out);
}